// Round 6
// baseline (26.730 us; speedup 1.0000x reference)
//
#include <hip/hip_runtime.h>

#define KH 512
#define KW 512
#define TW 4

__global__ __launch_bounds__(256, 8)
void TrainableFilter_75118978007282_kernel(const float* __restrict__ x,
                                           const float* __restrict__ wsp,
                                           float* __restrict__ out) {
    // block (64,4); each thread computes TW=4 horizontally adjacent pixels of one row
    const int tx = threadIdx.x;
    const int w0 = blockIdx.x * (64 * TW) + tx * TW;
    const int h  = blockIdx.y * 4 + threadIdx.y;
    const int plane = blockIdx.z;
    const float* __restrict__ xp = x + (size_t)plane * KH * KW;

    // edge lanes: clamp segment bases; reflected values recovered via cndmask
    const bool left  = (w0 == 0);
    const bool right = (w0 == KW - TW);
    const int b0 = left ? 0 : (w0 - 4);
    const int b2 = right ? (KW - 4) : (w0 + 4);

    // center pixels (aligned float4, always in-bounds)
    const float4 cv = *reinterpret_cast<const float4*>(xp + (size_t)h * KW + w0);
    const float c0 = cv.x, c1 = cv.y, c2 = cv.z, c3 = cv.w;

    float num0 = 0.f, num1 = 0.f, num2 = 0.f, num3 = 0.f;
    float den0 = 0.f, den1 = 0.f, den2 = 0.f, den3 = 0.f;

    const float S = 0.84932184f;  // sqrt(0.5*log2(e)); exp(-0.5 d^2) = exp2(-(d*S)^2)

#pragma unroll
    for (int ki = 0; ki < 5; ++ki) {
        int hh = h + ki - 2;
        hh = (hh < 0) ? -hh : hh;
        hh = (hh >= KH) ? (2 * KH - 2 - hh) : hh;
        const float* __restrict__ rp = xp + (size_t)hh * KW;

        const float4 s0 = *reinterpret_cast<const float4*>(rp + b0);
        const float4 s1 = *reinterpret_cast<const float4*>(rp + w0);
        const float4 s2 = *reinterpret_cast<const float4*>(rp + b2);
        float win[12] = { s0.x, s0.y, s0.z, s0.w,
                          s1.x, s1.y, s1.z, s1.w,
                          s2.x, s2.y, s2.z, s2.w };
        // reflect fixups (register selects, no extra loads):
        //  left  (w0==0,  b0 clamped to 0):   win[2] wants col -2 -> 2 (already there);
        //                                     win[3] wants col -1 -> 1 = win[1]
        //  right (w0==508, b2 clamped to 508): win[8] wants 512 -> 510 = win[6];
        //                                      win[9] wants 513 -> 509 = win[5]
        win[3] = left ? win[1] : win[3];
        const float f8 = right ? win[6] : win[8];
        const float f9 = right ? win[5] : win[9];
        win[8] = f8; win[9] = f9;

#pragma unroll
        for (int j = 0; j < 5; ++j) {
            const float wk = wsp[ki * 5 + j];  // uniform + static offset -> s_load
            {
                const float p = win[2 + 0 + j];
                const float t = (p - c0) * S;
                const float g = __builtin_amdgcn_exp2f(-t * t) * wk;
                num0 = fmaf(g, p, num0); den0 += g;
            }
            {
                const float p = win[2 + 1 + j];
                const float t = (p - c1) * S;
                const float g = __builtin_amdgcn_exp2f(-t * t) * wk;
                num1 = fmaf(g, p, num1); den1 += g;
            }
            {
                const float p = win[2 + 2 + j];
                const float t = (p - c2) * S;
                const float g = __builtin_amdgcn_exp2f(-t * t) * wk;
                num2 = fmaf(g, p, num2); den2 += g;
            }
            {
                const float p = win[2 + 3 + j];
                const float t = (p - c3) * S;
                const float g = __builtin_amdgcn_exp2f(-t * t) * wk;
                num3 = fmaf(g, p, num3); den3 += g;
            }
        }
    }

    float4 o;
    o.x = __fdividef(num0, den0);
    o.y = __fdividef(num1, den1);
    o.z = __fdividef(num2, den2);
    o.w = __fdividef(num3, den3);
    *reinterpret_cast<float4*>(out + (size_t)plane * KH * KW + (size_t)h * KW + w0) = o;
}

extern "C" void kernel_launch(void* const* d_in, const int* in_sizes, int n_in,
                              void* d_out, int out_size, void* d_ws, size_t ws_size,
                              hipStream_t stream) {
    const float* x   = (const float*)d_in[0];
    const float* wsp = (const float*)d_in[1];
    float* out = (float*)d_out;

    const int planes = out_size / (KH * KW);  // B*C = 12

    dim3 block(64, 4, 1);
    dim3 grid(KW / (64 * TW), KH / 4, planes);
    TrainableFilter_75118978007282_kernel<<<grid, block, 0, stream>>>(x, wsp, out);
}

// Round 7
// 21.621 us; speedup vs baseline: 1.2363x; 1.2363x over previous
//
#include <hip/hip_runtime.h>

#define KH 512
#define KW 512
#define TW 4

typedef float f32x2 __attribute__((ext_vector_type(2)));

__global__ __launch_bounds__(256)
void TrainableFilter_75118978007282_kernel(const float* __restrict__ x,
                                           const float* __restrict__ wsp,
                                           float* __restrict__ out) {
    // block (64,4); each thread computes TW=4 adjacent pixels of one row,
    // processed as two f32x2 pairs to get v_pk_*_f32 packed math.
    const int tx = threadIdx.x;
    const int w0 = blockIdx.x * (64 * TW) + tx * TW;
    const int h  = blockIdx.y * 4 + threadIdx.y;
    const int plane = blockIdx.z;
    const float* __restrict__ xp = x + (size_t)plane * KH * KW;

    const bool left  = (w0 == 0);
    const bool right = (w0 == KW - TW);
    const int b0 = left ? 0 : (w0 - 4);
    const int b2 = right ? (KW - 4) : (w0 + 4);

    const float4 cv = *reinterpret_cast<const float4*>(xp + (size_t)h * KW + w0);
    const f32x2 c01 = {cv.x, cv.y};
    const f32x2 c23 = {cv.z, cv.w};

    // center tap (ki=2,j=2): d==0, g==wsp[12] exactly -> fold into init
    const float w12 = wsp[12];
    f32x2 num01 = {0.f, 0.f}, num23 = {0.f, 0.f};
    f32x2 den01 = {w12, w12}, den23 = {w12, w12};

    const float NC2 = -0.72134752f;  // -0.5*log2(e): exp(-0.5 d^2) = exp2(d^2*NC2)

#pragma unroll
    for (int ki = 0; ki < 5; ++ki) {
        int hh = h + ki - 2;
        hh = (hh < 0) ? -hh : hh;
        hh = (hh >= KH) ? (2 * KH - 2 - hh) : hh;
        const float* __restrict__ rp = xp + (size_t)hh * KW;

        const float4 s0 = *reinterpret_cast<const float4*>(rp + b0);
        const float4 s1 = *reinterpret_cast<const float4*>(rp + w0);
        const float4 s2 = *reinterpret_cast<const float4*>(rp + b2);
        float win[12] = { s0.x, s0.y, s0.z, s0.w,
                          s1.x, s1.y, s1.z, s1.w,
                          s2.x, s2.y, s2.z, s2.w };
        // reflect fixups (register selects, no extra loads)
        win[3] = left ? win[1] : win[3];
        const float f8 = right ? win[6] : win[8];
        const float f9 = right ? win[5] : win[9];
        win[8] = f8; win[9] = f9;

#pragma unroll
        for (int j = 0; j < 5; ++j) {
            if (ki == 2 && j == 2) continue;   // folded into den init
            const float wkv = wsp[ki * 5 + j]; // uniform -> SGPR
            {
                const f32x2 p = {win[2 + j], win[3 + j]};
                const f32x2 d = p - c01;
                const f32x2 t = d * NC2;
                const f32x2 a = d * t;         // d^2 * NC2  (<= 0)
                f32x2 e;
                e.x = __builtin_amdgcn_exp2f(a.x);
                e.y = __builtin_amdgcn_exp2f(a.y);
                const f32x2 g = e * wkv;
                num01 = num01 + g * d;         // ffp-contract -> v_pk_fma_f32
                den01 = den01 + g;
            }
            {
                const f32x2 p = {win[4 + j], win[5 + j]};
                const f32x2 d = p - c23;
                const f32x2 t = d * NC2;
                const f32x2 a = d * t;
                f32x2 e;
                e.x = __builtin_amdgcn_exp2f(a.x);
                e.y = __builtin_amdgcn_exp2f(a.y);
                const f32x2 g = e * wkv;
                num23 = num23 + g * d;
                den23 = den23 + g;
            }
        }
    }

    float4 o;
    o.x = cv.x + __fdividef(num01.x, den01.x);
    o.y = cv.y + __fdividef(num01.y, den01.y);
    o.z = cv.z + __fdividef(num23.x, den23.x);
    o.w = cv.w + __fdividef(num23.y, den23.y);
    *reinterpret_cast<float4*>(out + (size_t)plane * KH * KW + (size_t)h * KW + w0) = o;
}

extern "C" void kernel_launch(void* const* d_in, const int* in_sizes, int n_in,
                              void* d_out, int out_size, void* d_ws, size_t ws_size,
                              hipStream_t stream) {
    const float* x   = (const float*)d_in[0];
    const float* wsp = (const float*)d_in[1];
    float* out = (float*)d_out;

    const int planes = out_size / (KH * KW);  // B*C = 12

    dim3 block(64, 4, 1);
    dim3 grid(KW / (64 * TW), KH / 4, planes);
    TrainableFilter_75118978007282_kernel<<<grid, block, 0, stream>>>(x, wsp, out);
}